// Round 1
// baseline (127.254 us; speedup 1.0000x reference)
//
#include <hip/hip_runtime.h>
#include <math.h>

#define BB 16
#define NN 16000
#define GG 128
#define NPG (NN + GG)

__device__ __forceinline__ float box_iou1(float4 a, float4 b) {
    float area_a = (a.z - a.x) * (a.w - a.y);
    float area_b = (b.z - b.x) * (b.w - b.y);
    float ltx = fmaxf(a.x, b.x), lty = fmaxf(a.y, b.y);
    float rbx = fminf(a.z, b.z), rby = fminf(a.w, b.w);
    float w = fmaxf(rbx - ltx, 0.0f), h = fmaxf(rby - lty, 0.0f);
    float inter = w * h;
    return inter / (area_a + area_b - inter);
}

// Kernel 1: per (b, p) over p in [0, N+G): labels + pred_boxes
__global__ __launch_bounds__(256) void k_pred_labels(
    const float4* __restrict__ props,   // B*N
    const float4* __restrict__ gts,     // B*G
    const float4* __restrict__ reg,     // B*(N+G)
    float4* __restrict__ pred,          // B*(N+G)
    float* __restrict__ labels)         // B*(N+G)
{
    __shared__ float4 sgt[GG];
    const int b = blockIdx.y;
    const int p = blockIdx.x * 256 + threadIdx.x;
    if (threadIdx.x < GG) sgt[threadIdx.x] = gts[b * GG + threadIdx.x];
    __syncthreads();
    if (p >= NPG) return;

    float4 pb = (p < NN) ? props[b * NN + p] : gts[b * GG + (p - NN)];

    float m = 0.0f;
    #pragma unroll 8
    for (int g = 0; g < GG; ++g) m = fmaxf(m, box_iou1(sgt[g], pb));
    labels[b * NPG + p] = (m >= 0.5f) ? 1.0f : 0.0f;

    // decode + clip
    float4 r = reg[b * NPG + p];
    float pw = pb.z - pb.x, ph = pb.w - pb.y;
    float pcx = pb.x + 0.5f * pw, pcy = pb.y + 0.5f * ph;
    const float CLIPV = 4.135166556742356f;  // log(1000/16)
    float dx = r.x / 10.0f, dy = r.y / 10.0f;
    float dw = fminf(r.z / 5.0f, CLIPV), dh = fminf(r.w / 5.0f, CLIPV);
    float ncx = dx * pw + pcx, ncy = dy * ph + pcy;
    float nw = expf(dw) * pw, nh = expf(dh) * ph;
    float4 o;
    o.x = fminf(fmaxf(ncx - 0.5f * nw, 0.0f), 800.0f);
    o.y = fminf(fmaxf(ncy - 0.5f * nh, 0.0f), 800.0f);
    o.z = fminf(fmaxf(ncx + 0.5f * nw, 0.0f), 800.0f);
    o.w = fminf(fmaxf(ncy + 0.5f * nh, 0.0f), 800.0f);
    pred[b * NPG + p] = o;
}

// Kernel 2: one block per (g, b): argmax IoU over N proposals (first-max
// tie-break to match jnp.argmax), roi_scores + encode(reg_targets)
__global__ __launch_bounds__(256) void k_match(
    const float4* __restrict__ props,   // B*N
    const float4* __restrict__ gts,     // B*G
    float4* __restrict__ reg_targets,   // B*G
    float* __restrict__ roi_scores)     // B*G
{
    const int g = blockIdx.x, b = blockIdx.y;
    const float4 gb = gts[b * GG + g];
    const float4* pp = props + (size_t)b * NN;

    float best = -1.0f;
    int bidx = 0;
    for (int p = threadIdx.x; p < NN; p += 256) {
        float v = box_iou1(gb, pp[p]);
        if (v > best) { best = v; bidx = p; }   // strict > keeps smallest p per thread
    }

    __shared__ float sval[256];
    __shared__ int sidx[256];
    sval[threadIdx.x] = best;
    sidx[threadIdx.x] = bidx;
    __syncthreads();
    for (int s = 128; s > 0; s >>= 1) {
        if (threadIdx.x < s) {
            float v2 = sval[threadIdx.x + s];
            int i2 = sidx[threadIdx.x + s];
            if (v2 > sval[threadIdx.x] ||
                (v2 == sval[threadIdx.x] && i2 < sidx[threadIdx.x])) {
                sval[threadIdx.x] = v2;
                sidx[threadIdx.x] = i2;
            }
        }
        __syncthreads();
    }

    if (threadIdx.x == 0) {
        int mi = sidx[0];
        roi_scores[b * GG + g] = sval[0];
        float4 pb = pp[mi];
        float pw = pb.z - pb.x, ph = pb.w - pb.y;
        float pcx = pb.x + 0.5f * pw, pcy = pb.y + 0.5f * ph;
        float gw = gb.z - gb.x, gh = gb.w - gb.y;
        float gcx = gb.x + 0.5f * gw, gcy = gb.y + 0.5f * gh;
        float4 t;
        t.x = 10.0f * (gcx - pcx) / pw;
        t.y = 10.0f * (gcy - pcy) / ph;
        t.z = 5.0f * logf(gw / pw);
        t.w = 5.0f * logf(gh / ph);
        reg_targets[b * GG + g] = t;
    }
}

extern "C" void kernel_launch(void* const* d_in, const int* in_sizes, int n_in,
                              void* d_out, int out_size, void* d_ws, size_t ws_size,
                              hipStream_t stream) {
    const float4* props = (const float4*)d_in[0];   // (B, N, 4)
    const float4* gts   = (const float4*)d_in[1];   // (B, G, 4)
    const float4* reg   = (const float4*)d_in[2];   // (B, N+G, 4)

    float* out = (float*)d_out;
    float4* pred   = (float4*)out;                                  // (B, N+G, 4)
    float4* regt   = (float4*)(out + (size_t)BB * NPG * 4);         // (B, G, 4)
    float*  roi    = out + (size_t)BB * NPG * 4 + (size_t)BB * GG * 4;  // (B, G)
    float*  labels = roi + (size_t)BB * GG;                         // (B, N+G)

    dim3 grid1((NPG + 255) / 256, BB, 1);
    k_pred_labels<<<grid1, 256, 0, stream>>>(props, gts, reg, pred, labels);

    dim3 grid2(GG, BB, 1);
    k_match<<<grid2, 256, 0, stream>>>(props, gts, regt, roi);
}

// Round 5
// 120.524 us; speedup vs baseline: 1.0558x; 1.0558x over previous
//
#include <hip/hip_runtime.h>
#include <math.h>

#define BB 16
#define NN 16000
#define GG 128
#define NPG (NN + GG)

typedef unsigned int u32;
typedef unsigned long long u64;

// Fused kernel: one thread per (b, p) column of the G x (N+G) IoU matrix.
//  - column max over g  -> labels
//  - decode+clip        -> pred_boxes
//  - row argmax over p<N (packed u64, first-max tie-break) -> gbest (d_ws)
__global__ __launch_bounds__(256) void k_fused(
    const float4* __restrict__ props,   // B*N
    const float4* __restrict__ gts,     // B*G
    const float4* __restrict__ reg,     // B*(N+G)
    float4* __restrict__ pred,          // B*(N+G)
    float* __restrict__ labels,         // B*(N+G)
    u64* __restrict__ gbest)            // B*G (zeroed)
{
    __shared__ u64 s_best[GG];
    const int b = blockIdx.y;
    const int base = blockIdx.x * 256;          // 63 * 256 == NPG exactly
    const int p = base + threadIdx.x;
    const u64 initv = (u64)(~(u32)base);        // pack(v=0.0f, idx=base)
    if (threadIdx.x < GG) s_best[threadIdx.x] = initv;
    __syncthreads();

    const bool isprop = (p < NN);
    float4 pb = isprop ? props[b * NN + p] : gts[b * GG + (p - NN)];
    const float area_p = (pb.z - pb.x) * (pb.w - pb.y);
    const float4* __restrict__ gtb = gts + b * GG;  // wave-uniform addr -> s_load

    float m = 0.0f;
    #pragma unroll 4
    for (int g = 0; g < GG; ++g) {
        float4 gb = gtb[g];
        float area_g = (gb.z - gb.x) * (gb.w - gb.y);
        float ltx = fmaxf(gb.x, pb.x), lty = fmaxf(gb.y, pb.y);
        float rbx = fminf(gb.z, pb.z), rby = fminf(gb.w, pb.w);
        float w = fmaxf(rbx - ltx, 0.0f), h = fmaxf(rby - lty, 0.0f);
        float inter = w * h;
        float v = inter / (area_g + area_p - inter);   // IEEE div, matches np
        m = fmaxf(m, v);
        if (isprop) {
            u32 chi = __float_as_uint(v);              // v >= 0 -> monotone bits
            u32 clo = ~(u32)p;                         // larger = smaller index
            volatile u32* sb = (volatile u32*)&s_best[g];
            u32 hi = sb[1];                            // hi BEFORE lo: monotone
            u32 lo = sb[0];                            //  growth => safe skip
            if (chi > hi || (chi == hi && clo > lo)) {
                atomicMax(&s_best[g], ((u64)chi << 32) | clo);
            }
        }
    }

    labels[b * NPG + p] = (m >= 0.5f) ? 1.0f : 0.0f;

    // decode + clip (pred_boxes)
    {
        float4 r = reg[b * NPG + p];
        float pw = pb.z - pb.x, ph = pb.w - pb.y;
        float pcx = pb.x + 0.5f * pw, pcy = pb.y + 0.5f * ph;
        const float CLIPV = 4.135166556742356f;  // log(1000/16)
        float dx = r.x / 10.0f, dy = r.y / 10.0f;
        float dw = fminf(r.z / 5.0f, CLIPV), dh = fminf(r.w / 5.0f, CLIPV);
        float ncx = dx * pw + pcx, ncy = dy * ph + pcy;
        float nw = expf(dw) * pw, nh = expf(dh) * ph;
        float4 o;
        o.x = fminf(fmaxf(ncx - 0.5f * nw, 0.0f), 800.0f);
        o.y = fminf(fmaxf(ncy - 0.5f * nh, 0.0f), 800.0f);
        o.z = fminf(fmaxf(ncx + 0.5f * nw, 0.0f), 800.0f);
        o.w = fminf(fmaxf(ncy + 0.5f * nh, 0.0f), 800.0f);
        pred[b * NPG + p] = o;
    }

    __syncthreads();
    if (threadIdx.x < GG) {
        u64 v = s_best[threadIdx.x];
        // block 0 must always merge (carries the all-zero-row -> idx 0 case);
        // other blocks skip untouched rows to cut global atomics
        if (base == 0 || v != initv)
            atomicMax(&gbest[b * GG + threadIdx.x], v);
    }
}

// Finalize: unpack winners -> roi_scores + encode -> reg_targets
__global__ __launch_bounds__(256) void k_finalize(
    const float4* __restrict__ props,
    const float4* __restrict__ gts,
    const u64* __restrict__ gbest,
    float4* __restrict__ regt,
    float* __restrict__ roi)
{
    int t = blockIdx.x * 256 + threadIdx.x;
    if (t >= BB * GG) return;
    int b = t / GG;
    u64 wv = gbest[t];
    float val = __uint_as_float((u32)(wv >> 32));
    int idx = (int)(~(u32)wv);
    roi[t] = val;

    float4 pb = props[b * NN + idx];
    float4 gb = gts[t];
    float pw = pb.z - pb.x, ph = pb.w - pb.y;
    float pcx = pb.x + 0.5f * pw, pcy = pb.y + 0.5f * ph;
    float gw = gb.z - gb.x, gh = gb.w - gb.y;
    float gcx = gb.x + 0.5f * gw, gcy = gb.y + 0.5f * gh;
    float4 tt;
    tt.x = 10.0f * (gcx - pcx) / pw;
    tt.y = 10.0f * (gcy - pcy) / ph;
    tt.z = 5.0f * logf(gw / pw);
    tt.w = 5.0f * logf(gh / ph);
    regt[t] = tt;
}

extern "C" void kernel_launch(void* const* d_in, const int* in_sizes, int n_in,
                              void* d_out, int out_size, void* d_ws, size_t ws_size,
                              hipStream_t stream) {
    const float4* props = (const float4*)d_in[0];   // (B, N, 4)
    const float4* gts   = (const float4*)d_in[1];   // (B, G, 4)
    const float4* reg   = (const float4*)d_in[2];   // (B, N+G, 4)

    float* out = (float*)d_out;
    float4* pred   = (float4*)out;                                      // (B, N+G, 4)
    float4* regt   = (float4*)(out + (size_t)BB * NPG * 4);             // (B, G, 4)
    float*  roi    = out + (size_t)BB * NPG * 4 + (size_t)BB * GG * 4;  // (B, G)
    float*  labels = roi + (size_t)BB * GG;                             // (B, N+G)

    u64* gbest = (u64*)d_ws;
    hipMemsetAsync(gbest, 0, (size_t)BB * GG * sizeof(u64), stream);

    dim3 grid1(NPG / 256, BB, 1);   // 63 x 16
    k_fused<<<grid1, 256, 0, stream>>>(props, gts, reg, pred, labels, gbest);

    k_finalize<<<(BB * GG + 255) / 256, 256, 0, stream>>>(props, gts, gbest, regt, roi);
}

// Round 6
// 100.915 us; speedup vs baseline: 1.2610x; 1.1943x over previous
//
#include <hip/hip_runtime.h>
#include <math.h>

#define BB 16
#define NN 16000
#define GG 128
#define NPG (NN + GG)

typedef unsigned int u32;
typedef unsigned long long u64;

// Fused kernel: one thread per (b, p) column of the G x (N+G) IoU matrix.
//  - column max over g  -> labels
//  - decode+clip        -> pred_boxes
//  - row argmax over p<N (packed u64, first-max tie-break) -> gbest (d_ws)
//
// Sparsity: ~99.3% of (g,p) pairs have zero intersection. The inner loop is
// pure VALU (no LDS, no div); a wave-uniform __ballot branch gates the IEEE
// div + m-update + fire-and-forget ds_max_u64 (taken ~36% of iters, and the
// atomic fires for ~1 lane/thread total). Zero-inter lanes inside the taken
// branch compute v = 0/union = 0.0 exactly — bit-identical to the reference.
__global__ __launch_bounds__(256) void k_fused(
    const float4* __restrict__ props,   // B*N
    const float4* __restrict__ gts,     // B*G
    const float4* __restrict__ reg,     // B*(N+G)
    float4* __restrict__ pred,          // B*(N+G)
    float* __restrict__ labels,         // B*(N+G)
    u64* __restrict__ gbest)            // B*G (zeroed)
{
    __shared__ u64 s_best[GG];
    const int b = blockIdx.y;
    const int base = blockIdx.x * 256;          // 63 * 256 == NPG exactly
    const int p = base + threadIdx.x;
    const u64 initv = (u64)(~(u32)base);        // pack(v=0.0f, idx=base)
    if (threadIdx.x < GG) s_best[threadIdx.x] = initv;
    __syncthreads();

    const bool isprop = (p < NN);               // wave-uniform (128-aligned split)
    float4 pb = isprop ? props[b * NN + p] : gts[b * GG + (p - NN)];
    const float area_p = (pb.z - pb.x) * (pb.w - pb.y);
    const float4* __restrict__ gtb = gts + b * GG;  // wave-uniform addr -> s_load

    float m = 0.0f;
    #pragma unroll 4
    for (int g = 0; g < GG; ++g) {
        float4 gb = gtb[g];
        float ltx = fmaxf(gb.x, pb.x), lty = fmaxf(gb.y, pb.y);
        float rbx = fminf(gb.z, pb.z), rby = fminf(gb.w, pb.w);
        float w = fmaxf(rbx - ltx, 0.0f), h = fmaxf(rby - lty, 0.0f);
        float inter = w * h;
        if (__ballot(inter > 0.0f)) {           // wave-uniform: no if-conversion
            float area_g = (gb.z - gb.x) * (gb.w - gb.y);
            float v = inter / (area_g + area_p - inter);   // IEEE div, = np
            m = fmaxf(m, v);                    // v==0.0 for zero-inter lanes
            if (isprop && inter > 0.0f) {
                // fire-and-forget ds_max_u64: no return, no dependent wait
                atomicMax(&s_best[g],
                          ((u64)__float_as_uint(v) << 32) | (u32)(~(u32)p));
            }
        }
    }

    labels[b * NPG + p] = (m >= 0.5f) ? 1.0f : 0.0f;

    // decode + clip (pred_boxes)
    {
        float4 r = reg[b * NPG + p];
        float pw = pb.z - pb.x, ph = pb.w - pb.y;
        float pcx = pb.x + 0.5f * pw, pcy = pb.y + 0.5f * ph;
        const float CLIPV = 4.135166556742356f;  // log(1000/16)
        float dx = r.x / 10.0f, dy = r.y / 10.0f;
        float dw = fminf(r.z / 5.0f, CLIPV), dh = fminf(r.w / 5.0f, CLIPV);
        float ncx = dx * pw + pcx, ncy = dy * ph + pcy;
        float nw = expf(dw) * pw, nh = expf(dh) * ph;
        float4 o;
        o.x = fminf(fmaxf(ncx - 0.5f * nw, 0.0f), 800.0f);
        o.y = fminf(fmaxf(ncy - 0.5f * nh, 0.0f), 800.0f);
        o.z = fminf(fmaxf(ncx + 0.5f * nw, 0.0f), 800.0f);
        o.w = fminf(fmaxf(ncy + 0.5f * nh, 0.0f), 800.0f);
        pred[b * NPG + p] = o;
    }

    __syncthreads();   // also drains the ds_max_u64 ops
    if (threadIdx.x < GG) {
        u64 v = s_best[threadIdx.x];
        // block 0 must always merge (carries the all-zero-row -> idx 0 case);
        // other blocks skip untouched rows to cut global atomics
        if (base == 0 || v != initv)
            atomicMax(&gbest[b * GG + threadIdx.x], v);
    }
}

// Finalize: unpack winners -> roi_scores + encode -> reg_targets
__global__ __launch_bounds__(256) void k_finalize(
    const float4* __restrict__ props,
    const float4* __restrict__ gts,
    const u64* __restrict__ gbest,
    float4* __restrict__ regt,
    float* __restrict__ roi)
{
    int t = blockIdx.x * 256 + threadIdx.x;
    if (t >= BB * GG) return;
    int b = t / GG;
    u64 wv = gbest[t];
    float val = __uint_as_float((u32)(wv >> 32));
    int idx = (int)(~(u32)wv);
    roi[t] = val;

    float4 pb = props[b * NN + idx];
    float4 gb = gts[t];
    float pw = pb.z - pb.x, ph = pb.w - pb.y;
    float pcx = pb.x + 0.5f * pw, pcy = pb.y + 0.5f * ph;
    float gw = gb.z - gb.x, gh = gb.w - gb.y;
    float gcx = gb.x + 0.5f * gw, gcy = gb.y + 0.5f * gh;
    float4 tt;
    tt.x = 10.0f * (gcx - pcx) / pw;
    tt.y = 10.0f * (gcy - pcy) / ph;
    tt.z = 5.0f * logf(gw / pw);
    tt.w = 5.0f * logf(gh / ph);
    regt[t] = tt;
}

extern "C" void kernel_launch(void* const* d_in, const int* in_sizes, int n_in,
                              void* d_out, int out_size, void* d_ws, size_t ws_size,
                              hipStream_t stream) {
    const float4* props = (const float4*)d_in[0];   // (B, N, 4)
    const float4* gts   = (const float4*)d_in[1];   // (B, G, 4)
    const float4* reg   = (const float4*)d_in[2];   // (B, N+G, 4)

    float* out = (float*)d_out;
    float4* pred   = (float4*)out;                                      // (B, N+G, 4)
    float4* regt   = (float4*)(out + (size_t)BB * NPG * 4);             // (B, G, 4)
    float*  roi    = out + (size_t)BB * NPG * 4 + (size_t)BB * GG * 4;  // (B, G)
    float*  labels = roi + (size_t)BB * GG;                             // (B, N+G)

    u64* gbest = (u64*)d_ws;
    hipMemsetAsync(gbest, 0, (size_t)BB * GG * sizeof(u64), stream);

    dim3 grid1(NPG / 256, BB, 1);   // 63 x 16
    k_fused<<<grid1, 256, 0, stream>>>(props, gts, reg, pred, labels, gbest);

    k_finalize<<<(BB * GG + 255) / 256, 256, 0, stream>>>(props, gts, gbest, regt, roi);
}

// Round 7
// 96.499 us; speedup vs baseline: 1.3187x; 1.0458x over previous
//
#include <hip/hip_runtime.h>
#include <math.h>

#define BB 16
#define NN 16000
#define GG 128
#define NPG (NN + GG)
#define NSPLIT 4
#define GSUB (GG / NSPLIT)   // 32 gt rows per block

typedef unsigned int u32;
typedef unsigned long long u64;

// IoU pass, g-split 4 ways for occupancy: grid (63, B, NSPLIT).
// Each block: 256 columns (p) x 32 gt rows.
//  - partial column max over its g-subrange -> mpart (d_ws)
//  - row argmax over p<N (packed u64, first-max tie-break) -> gbest (d_ws)
// Sparsity: ~99% of pairs have zero intersection; wave-uniform __ballot gates
// the IEEE div + atomic (zero-inter lanes in a taken branch compute exactly
// 0.0, preserving bit-exactness vs the reference).
__global__ __launch_bounds__(256) void k_iou(
    const float4* __restrict__ props,   // B*N
    const float4* __restrict__ gts,     // B*G
    float* __restrict__ mpart,          // NSPLIT * B * NPG
    u64* __restrict__ gbest)            // B*G (zeroed)
{
    __shared__ u64 s_best[GSUB];
    const int b = blockIdx.y;
    const int g0 = blockIdx.z * GSUB;
    const int base = blockIdx.x * 256;          // 63 * 256 == NPG exactly
    const int p = base + threadIdx.x;
    const u64 initv = (u64)(~(u32)base);        // pack(v=0.0f, idx=base)
    if (threadIdx.x < GSUB) s_best[threadIdx.x] = initv;
    __syncthreads();

    const bool isprop = (p < NN);               // wave-uniform (128-aligned split)
    float4 pb = isprop ? props[b * NN + p] : gts[b * GG + (p - NN)];
    const float area_p = (pb.z - pb.x) * (pb.w - pb.y);
    const float4* __restrict__ gtb = gts + b * GG + g0;  // wave-uniform -> s_load

    float m = 0.0f;
    #pragma unroll 4
    for (int g = 0; g < GSUB; ++g) {
        float4 gb = gtb[g];
        float ltx = fmaxf(gb.x, pb.x), lty = fmaxf(gb.y, pb.y);
        float rbx = fminf(gb.z, pb.z), rby = fminf(gb.w, pb.w);
        float w = fmaxf(rbx - ltx, 0.0f), h = fmaxf(rby - lty, 0.0f);
        float inter = w * h;
        if (__ballot(inter > 0.0f)) {           // wave-uniform branch
            float area_g = (gb.z - gb.x) * (gb.w - gb.y);
            float v = inter / (area_g + area_p - inter);   // IEEE div, = np
            m = fmaxf(m, v);                    // v==0.0 for zero-inter lanes
            if (isprop && inter > 0.0f) {
                // fire-and-forget ds_max_u64: no return, no dependent wait
                atomicMax(&s_best[g],
                          ((u64)__float_as_uint(v) << 32) | (u32)(~(u32)p));
            }
        }
    }

    // every (split,b,p) slot written unconditionally -> poison-safe
    mpart[((size_t)blockIdx.z * BB + b) * NPG + p] = m;

    __syncthreads();   // drains ds atomics
    if (threadIdx.x < GSUB) {
        u64 v = s_best[threadIdx.x];
        // base==0 block always merges (carries all-zero-row -> idx 0 case)
        if (base == 0 || v != initv)
            atomicMax(&gbest[b * GG + g0 + threadIdx.x], v);
    }
}

// Merge partial maxima -> labels; decode + clip -> pred_boxes
__global__ __launch_bounds__(256) void k_merge(
    const float4* __restrict__ props,
    const float4* __restrict__ gts,
    const float4* __restrict__ reg,
    const float* __restrict__ mpart,
    float4* __restrict__ pred,
    float* __restrict__ labels)
{
    const int b = blockIdx.y;
    const int p = blockIdx.x * 256 + threadIdx.x;
    const size_t col = (size_t)b * NPG + p;

    float m = fmaxf(fmaxf(mpart[col],                         mpart[(size_t)BB * NPG + col]),
                    fmaxf(mpart[(size_t)2 * BB * NPG + col],  mpart[(size_t)3 * BB * NPG + col]));
    labels[col] = (m >= 0.5f) ? 1.0f : 0.0f;

    float4 pb = (p < NN) ? props[b * NN + p] : gts[b * GG + (p - NN)];
    float4 r = reg[col];
    float pw = pb.z - pb.x, ph = pb.w - pb.y;
    float pcx = pb.x + 0.5f * pw, pcy = pb.y + 0.5f * ph;
    const float CLIPV = 4.135166556742356f;  // log(1000/16)
    float dx = r.x / 10.0f, dy = r.y / 10.0f;
    float dw = fminf(r.z / 5.0f, CLIPV), dh = fminf(r.w / 5.0f, CLIPV);
    float ncx = dx * pw + pcx, ncy = dy * ph + pcy;
    float nw = expf(dw) * pw, nh = expf(dh) * ph;
    float4 o;
    o.x = fminf(fmaxf(ncx - 0.5f * nw, 0.0f), 800.0f);
    o.y = fminf(fmaxf(ncy - 0.5f * nh, 0.0f), 800.0f);
    o.z = fminf(fmaxf(ncx + 0.5f * nw, 0.0f), 800.0f);
    o.w = fminf(fmaxf(ncy + 0.5f * nh, 0.0f), 800.0f);
    pred[col] = o;
}

// Finalize: unpack winners -> roi_scores + encode -> reg_targets
__global__ __launch_bounds__(256) void k_finalize(
    const float4* __restrict__ props,
    const float4* __restrict__ gts,
    const u64* __restrict__ gbest,
    float4* __restrict__ regt,
    float* __restrict__ roi)
{
    int t = blockIdx.x * 256 + threadIdx.x;
    if (t >= BB * GG) return;
    int b = t / GG;
    u64 wv = gbest[t];
    float val = __uint_as_float((u32)(wv >> 32));
    int idx = (int)(~(u32)wv);
    roi[t] = val;

    float4 pb = props[b * NN + idx];
    float4 gb = gts[t];
    float pw = pb.z - pb.x, ph = pb.w - pb.y;
    float pcx = pb.x + 0.5f * pw, pcy = pb.y + 0.5f * ph;
    float gw = gb.z - gb.x, gh = gb.w - gb.y;
    float gcx = gb.x + 0.5f * gw, gcy = gb.y + 0.5f * gh;
    float4 tt;
    tt.x = 10.0f * (gcx - pcx) / pw;
    tt.y = 10.0f * (gcy - pcy) / ph;
    tt.z = 5.0f * logf(gw / pw);
    tt.w = 5.0f * logf(gh / ph);
    regt[t] = tt;
}

extern "C" void kernel_launch(void* const* d_in, const int* in_sizes, int n_in,
                              void* d_out, int out_size, void* d_ws, size_t ws_size,
                              hipStream_t stream) {
    const float4* props = (const float4*)d_in[0];   // (B, N, 4)
    const float4* gts   = (const float4*)d_in[1];   // (B, G, 4)
    const float4* reg   = (const float4*)d_in[2];   // (B, N+G, 4)

    float* out = (float*)d_out;
    float4* pred   = (float4*)out;                                      // (B, N+G, 4)
    float4* regt   = (float4*)(out + (size_t)BB * NPG * 4);             // (B, G, 4)
    float*  roi    = out + (size_t)BB * NPG * 4 + (size_t)BB * GG * 4;  // (B, G)
    float*  labels = roi + (size_t)BB * GG;                             // (B, N+G)

    u64*   gbest = (u64*)d_ws;                                          // 16 KB
    float* mpart = (float*)((char*)d_ws + (size_t)BB * GG * sizeof(u64)); // 4.1 MB
    hipMemsetAsync(gbest, 0, (size_t)BB * GG * sizeof(u64), stream);

    dim3 grid1(NPG / 256, BB, NSPLIT);   // 63 x 16 x 4 = 4032 blocks
    k_iou<<<grid1, 256, 0, stream>>>(props, gts, mpart, gbest);

    dim3 grid2(NPG / 256, BB, 1);
    k_merge<<<grid2, 256, 0, stream>>>(props, gts, reg, mpart, pred, labels);

    k_finalize<<<(BB * GG + 255) / 256, 256, 0, stream>>>(props, gts, gbest, regt, roi);
}

// Round 9
// 94.602 us; speedup vs baseline: 1.3451x; 1.0201x over previous
//
#include <hip/hip_runtime.h>
#include <math.h>

#define BB 16
#define NN 16000
#define GG 128
#define NPG (NN + GG)
#define COLS 64              // columns per block
#define NWAVE 8              // waves per block (512 threads)
#define GSUB (GG / NWAVE)    // 16 gt rows per wave

typedef unsigned int u32;
typedef unsigned long long u64;

// One block = 64 columns x all 128 gt rows, split 16-rows-per-wave.
//  - per-thread partial column max -> LDS 8-way reduce -> labels (+ fused
//    decode/clip -> pred_boxes), no global partial buffer, no merge kernel
//  - row argmax via packed u64 LDS atomicMax (first-max tie-break), merged
//    to gbest by waves 2-3 while wave 0 writes labels/pred
// Sparsity: ~99% of pairs have zero intersection; wave-uniform __ballot
// gates the IEEE div + atomic. Zero-inter lanes inside a taken branch
// compute exactly 0.0 -> bit-identical to the reference.
__global__ __launch_bounds__(512) void k_main(
    const float4* __restrict__ props,   // B*N
    const float4* __restrict__ gts,     // B*G
    const float4* __restrict__ reg,     // B*(N+G)
    float4* __restrict__ pred,          // B*(N+G)
    float* __restrict__ labels,         // B*(N+G)
    u64* __restrict__ gbest)            // B*G (zeroed)
{
    __shared__ float smax[NWAVE][COLS];
    __shared__ u64 s_best[GG];
    const int b = blockIdx.y;
    const int c = threadIdx.x & (COLS - 1);
    const int wv = threadIdx.x >> 6;          // wave id 0..7
    const int g0 = wv * GSUB;
    const int p = blockIdx.x * COLS + c;
    const u64 initv = 0xFFFFFFFFull;          // pack(v=0.0, idx=0)
    if (threadIdx.x < GG) s_best[threadIdx.x] = initv;
    __syncthreads();

    const bool isprop = (blockIdx.x < NN / COLS);   // block-uniform (250 exact)
    float4 pb = isprop ? props[b * NN + p] : gts[b * GG + (p - NN)];
    const float area_p = (pb.z - pb.x) * (pb.w - pb.y);
    const float4* __restrict__ gtb = gts + b * GG + g0;  // wave-uniform -> s_load

    float m = 0.0f;
    #pragma unroll
    for (int g = 0; g < GSUB; ++g) {
        float4 gb = gtb[g];
        float ltx = fmaxf(gb.x, pb.x), lty = fmaxf(gb.y, pb.y);
        float rbx = fminf(gb.z, pb.z), rby = fminf(gb.w, pb.w);
        float w = fmaxf(rbx - ltx, 0.0f), h = fmaxf(rby - lty, 0.0f);
        float inter = w * h;
        if (__ballot(inter > 0.0f)) {           // wave-uniform branch
            float area_g = (gb.z - gb.x) * (gb.w - gb.y);
            float v = inter / (area_g + area_p - inter);   // IEEE div, = np
            m = fmaxf(m, v);                    // v==0.0 for zero-inter lanes
            if (isprop && inter > 0.0f) {
                // fire-and-forget ds_max_u64: no return, no dependent wait
                atomicMax(&s_best[g0 + g],
                          ((u64)__float_as_uint(v) << 32) | (u32)(~(u32)p));
            }
        }
    }

    smax[wv][c] = m;
    __syncthreads();   // also drains all ds atomics

    if (threadIdx.x < COLS) {
        // wave 0: 8-way column-max -> labels; fused decode+clip -> pred
        float m8 = smax[0][c];
        #pragma unroll
        for (int w = 1; w < NWAVE; ++w) m8 = fmaxf(m8, smax[w][c]);
        const size_t col = (size_t)b * NPG + p;
        labels[col] = (m8 >= 0.5f) ? 1.0f : 0.0f;

        float4 r = reg[col];
        float pw = pb.z - pb.x, ph = pb.w - pb.y;
        float pcx = pb.x + 0.5f * pw, pcy = pb.y + 0.5f * ph;
        const float CLIPV = 4.135166556742356f;  // log(1000/16)
        float dx = r.x / 10.0f, dy = r.y / 10.0f;
        float dw = fminf(r.z / 5.0f, CLIPV), dh = fminf(r.w / 5.0f, CLIPV);
        float ncx = dx * pw + pcx, ncy = dy * ph + pcy;
        float nw = expf(dw) * pw, nh = expf(dh) * ph;
        float4 o;
        o.x = fminf(fmaxf(ncx - 0.5f * nw, 0.0f), 800.0f);
        o.y = fminf(fmaxf(ncy - 0.5f * nh, 0.0f), 800.0f);
        o.z = fminf(fmaxf(ncx + 0.5f * nw, 0.0f), 800.0f);
        o.w = fminf(fmaxf(ncy + 0.5f * nh, 0.0f), 800.0f);
        pred[col] = o;
    } else if (threadIdx.x >= 128 && threadIdx.x < 128 + GG) {
        // waves 2-3: merge row winners to global (concurrent with wave 0)
        int g = threadIdx.x - 128;
        u64 v = s_best[g];
        // block x==0 always merges: carries the all-zero-row -> idx 0 default
        if (blockIdx.x == 0 || v != initv)
            atomicMax(&gbest[b * GG + g], v);
    }
}

// Finalize: unpack winners -> roi_scores + encode -> reg_targets
__global__ __launch_bounds__(256) void k_finalize(
    const float4* __restrict__ props,
    const float4* __restrict__ gts,
    const u64* __restrict__ gbest,
    float4* __restrict__ regt,
    float* __restrict__ roi)
{
    int t = blockIdx.x * 256 + threadIdx.x;
    if (t >= BB * GG) return;
    int b = t / GG;
    u64 wv = gbest[t];
    float val = __uint_as_float((u32)(wv >> 32));
    int idx = (int)(~(u32)wv);
    roi[t] = val;

    float4 pb = props[b * NN + idx];
    float4 gb = gts[t];
    float pw = pb.z - pb.x, ph = pb.w - pb.y;
    float pcx = pb.x + 0.5f * pw, pcy = pb.y + 0.5f * ph;
    float gw = gb.z - gb.x, gh = gb.w - gb.y;
    float gcx = gb.x + 0.5f * gw, gcy = gb.y + 0.5f * gh;
    float4 tt;
    tt.x = 10.0f * (gcx - pcx) / pw;
    tt.y = 10.0f * (gcy - pcy) / ph;
    tt.z = 5.0f * logf(gw / pw);
    tt.w = 5.0f * logf(gh / ph);
    regt[t] = tt;
}

extern "C" void kernel_launch(void* const* d_in, const int* in_sizes, int n_in,
                              void* d_out, int out_size, void* d_ws, size_t ws_size,
                              hipStream_t stream) {
    const float4* props = (const float4*)d_in[0];   // (B, N, 4)
    const float4* gts   = (const float4*)d_in[1];   // (B, G, 4)
    const float4* reg   = (const float4*)d_in[2];   // (B, N+G, 4)

    float* out = (float*)d_out;
    float4* pred   = (float4*)out;                                      // (B, N+G, 4)
    float4* regt   = (float4*)(out + (size_t)BB * NPG * 4);             // (B, G, 4)
    float*  roi    = out + (size_t)BB * NPG * 4 + (size_t)BB * GG * 4;  // (B, G)
    float*  labels = roi + (size_t)BB * GG;                             // (B, N+G)

    u64* gbest = (u64*)d_ws;                                            // 16 KB
    hipMemsetAsync(gbest, 0, (size_t)BB * GG * sizeof(u64), stream);

    dim3 grid1(NPG / COLS, BB, 1);   // 252 x 16 = 4032 blocks, 8 waves each
    k_main<<<grid1, 512, 0, stream>>>(props, gts, reg, pred, labels, gbest);

    k_finalize<<<(BB * GG + 255) / 256, 256, 0, stream>>>(props, gts, gbest, regt, roi);
}

// Round 11
// 92.074 us; speedup vs baseline: 1.3821x; 1.0274x over previous
//
#include <hip/hip_runtime.h>
#include <math.h>

#define BB 16
#define NN 16000
#define GG 128
#define NPG (NN + GG)
#define CHUNK 128            // columns per block: 2 streams x 64
#define NBLK (NPG / CHUNK)   // 126 blocks in x
#define PROPBLK (NN / CHUNK) // 125: blocks [0,125) all-prop, block 125 all-gt

typedef unsigned int u32;
typedef unsigned long long u64;

// g-in-lanes transpose: thread owns gt row g (registers), scans 64 columns.
//  - argmax over p: per-thread (v_bits, p) registers, ONE global atomicMax
//    at the end (packed u64, first-max tie-break == jnp.argmax). No LDS
//    atomics anywhere in the hot loop.
//  - labels: per-lane u64 bitmask (bit i = v>=0.5), shfl-OR reduce after
//    the loop; cross-wave OR via 32B of LDS.
//  - pb columns are wave-uniform -> s_load_dwordx4 (readfirstlane'd base).
//  - ~99% of pairs have zero intersection: one ballot branch per column
//    gates the IEEE div (untaken => v==0 exactly; bit-identical to ref).
__global__ __launch_bounds__(256) void k_main(
    const float4* __restrict__ props,   // B*N
    const float4* __restrict__ gts,     // B*G
    const float4* __restrict__ reg,     // B*(N+G)
    float4* __restrict__ pred,          // B*(N+G)
    float* __restrict__ labels,         // B*(N+G)
    u64* __restrict__ gbest)            // B*G (zeroed)
{
    __shared__ u64 lmask[2][2];
    const int b = blockIdx.y;
    const int w    = __builtin_amdgcn_readfirstlane((int)threadIdx.x >> 6);
    const int s    = w >> 1;            // column stream 0/1
    const int gw   = w & 1;             // g half 0/1
    const int lane = threadIdx.x & 63;
    const int g    = lane + (gw << 6);
    const int pbase = blockIdx.x * CHUNK + s * 64;
    const bool isprop = (blockIdx.x < PROPBLK);   // block-uniform

    const float4 gb = gts[b * GG + g];
    const float area_g = (gb.z - gb.x) * (gb.w - gb.y);

    // wave-uniform column pointer (block 125's columns live in gts)
    const float4* __restrict__ pcol =
        isprop ? (props + (size_t)b * NN + pbase)
               : (gts + (size_t)b * GG + (pbase - NN));

    u32 best_v = 0;          // float bits of best IoU (v>=0 -> monotone)
    u32 best_p = pbase;      // covers the all-zero-row -> idx-0 default
    u64 mask = 0;            // bit i: v(g, pbase+i) >= 0.5

    #pragma unroll 4
    for (int i = 0; i < 64; ++i) {
        float4 pb = pcol[i];                      // uniform addr -> s_load
        float ltx = fmaxf(gb.x, pb.x), lty = fmaxf(gb.y, pb.y);
        float rbx = fminf(gb.z, pb.z), rby = fminf(gb.w, pb.w);
        float iw = fmaxf(rbx - ltx, 0.0f), ih = fmaxf(rby - lty, 0.0f);
        float inter = iw * ih;
        if (__ballot(inter > 0.0f)) {             // wave-uniform branch
            float area_p = (pb.z - pb.x) * (pb.w - pb.y);
            float v = inter / ((area_g + area_p) - inter);  // IEEE div = np
            u32 vb = __float_as_uint(v);
            if (vb > best_v) { best_v = vb; best_p = pbase + i; } // strict >
            mask |= (v >= 0.5f) ? (1ull << i) : 0ull;
        }
    }

    // OR-reduce the label mask across the 64 lanes
    #pragma unroll
    for (int off = 32; off; off >>= 1)
        mask |= __shfl_xor((unsigned long long)mask, off, 64);
    if (lane == 0) lmask[s][gw] = mask;

    // merge this thread's row winner (prop blocks only; gt columns excluded)
    if (isprop)
        atomicMax(&gbest[b * GG + g], ((u64)best_v << 32) | (u32)(~best_p));

    __syncthreads();

    // epilogue: threads 0..127 finalize one column each
    if (threadIdx.x < 128) {
        const int ss = threadIdx.x >> 6, ii = threadIdx.x & 63;
        const int p = blockIdx.x * CHUNK + ss * 64 + ii;
        const size_t col = (size_t)b * NPG + p;
        u64 mm = lmask[ss][0] | lmask[ss][1];
        labels[col] = ((mm >> ii) & 1) ? 1.0f : 0.0f;

        float4 pb = isprop ? props[b * NN + p] : gts[b * GG + (p - NN)];
        float4 r = reg[col];
        float pw = pb.z - pb.x, ph = pb.w - pb.y;
        float pcx = pb.x + 0.5f * pw, pcy = pb.y + 0.5f * ph;
        const float CLIPV = 4.135166556742356f;  // log(1000/16)
        float dx = r.x / 10.0f, dy = r.y / 10.0f;
        float dw = fminf(r.z / 5.0f, CLIPV), dh = fminf(r.w / 5.0f, CLIPV);
        float ncx = dx * pw + pcx, ncy = dy * ph + pcy;
        float nw = expf(dw) * pw, nh = expf(dh) * ph;
        float4 o;
        o.x = fminf(fmaxf(ncx - 0.5f * nw, 0.0f), 800.0f);
        o.y = fminf(fmaxf(ncy - 0.5f * nh, 0.0f), 800.0f);
        o.z = fminf(fmaxf(ncx + 0.5f * nw, 0.0f), 800.0f);
        o.w = fminf(fmaxf(ncy + 0.5f * nh, 0.0f), 800.0f);
        pred[col] = o;
    }
}

// Finalize: unpack winners -> roi_scores + encode -> reg_targets
__global__ __launch_bounds__(256) void k_finalize(
    const float4* __restrict__ props,
    const float4* __restrict__ gts,
    const u64* __restrict__ gbest,
    float4* __restrict__ regt,
    float* __restrict__ roi)
{
    int t = blockIdx.x * 256 + threadIdx.x;
    if (t >= BB * GG) return;
    int b = t / GG;
    u64 wv = gbest[t];
    float val = __uint_as_float((u32)(wv >> 32));
    int idx = (int)(~(u32)wv);
    roi[t] = val;

    float4 pb = props[b * NN + idx];
    float4 gb = gts[t];
    float pw = pb.z - pb.x, ph = pb.w - pb.y;
    float pcx = pb.x + 0.5f * pw, pcy = pb.y + 0.5f * ph;
    float gw = gb.z - gb.x, gh = gb.w - gb.y;
    float gcx = gb.x + 0.5f * gw, gcy = gb.y + 0.5f * gh;
    float4 tt;
    tt.x = 10.0f * (gcx - pcx) / pw;
    tt.y = 10.0f * (gcy - pcy) / ph;
    tt.z = 5.0f * logf(gw / pw);
    tt.w = 5.0f * logf(gh / ph);
    regt[t] = tt;
}

extern "C" void kernel_launch(void* const* d_in, const int* in_sizes, int n_in,
                              void* d_out, int out_size, void* d_ws, size_t ws_size,
                              hipStream_t stream) {
    const float4* props = (const float4*)d_in[0];   // (B, N, 4)
    const float4* gts   = (const float4*)d_in[1];   // (B, G, 4)
    const float4* reg   = (const float4*)d_in[2];   // (B, N+G, 4)

    float* out = (float*)d_out;
    float4* pred   = (float4*)out;                                      // (B, N+G, 4)
    float4* regt   = (float4*)(out + (size_t)BB * NPG * 4);             // (B, G, 4)
    float*  roi    = out + (size_t)BB * NPG * 4 + (size_t)BB * GG * 4;  // (B, G)
    float*  labels = roi + (size_t)BB * GG;                             // (B, N+G)

    u64* gbest = (u64*)d_ws;                                            // 16 KB
    hipMemsetAsync(gbest, 0, (size_t)BB * GG * sizeof(u64), stream);

    dim3 grid1(NBLK, BB, 1);   // 126 x 16 = 2016 blocks, 4 waves each
    k_main<<<grid1, 256, 0, stream>>>(props, gts, reg, pred, labels, gbest);

    k_finalize<<<(BB * GG + 255) / 256, 256, 0, stream>>>(props, gts, gbest, regt, roi);
}